// Round 4
// baseline (201.045 us; speedup 1.0000x reference)
//
#include <hip/hip_runtime.h>
#include <hip/hip_bf16.h>
#include <cstdint>

// Problem constants (match reference)
#define Bn 8
#define Ln 4096
#define Dn 2048
#define Gn 32
#define GSn 64
static constexpr float EPS = 1e-5f;

// ---------------------------------------------------------------------------
// K1: per-(b,t,g) group means, written TRANSPOSED as mT[b,g,t] so K2 reads
// contiguously. One 256-thread block per row iter, grid-stride over 32768 rows.
// ---------------------------------------------------------------------------
__global__ __launch_bounds__(256) void k_group_means(const float* __restrict__ x,
                                                     float* __restrict__ mT) {
    const int tid = threadIdx.x;
    for (int row = blockIdx.x; row < Bn * Ln; row += gridDim.x) {
        const float4* xr = reinterpret_cast<const float4*>(x + (size_t)row * Dn) + tid * 2;
        float4 a = xr[0];
        float4 c = xr[1];
        float s = (a.x + a.y) + (a.z + a.w) + (c.x + c.y) + (c.z + c.w);
        // 8 lanes per group (wave-contiguous)
        s += __shfl_xor(s, 1);
        s += __shfl_xor(s, 2);
        s += __shfl_xor(s, 4);
        if ((tid & 7) == 0) {
            const int g = tid >> 3;
            const int b = row >> 12;           // row / Ln
            const int t = row & (Ln - 1);      // row % Ln
            mT[((size_t)(b * Gn + g)) * Ln + t] = s * (1.0f / (float)GSn);
        }
    }
}

// ---------------------------------------------------------------------------
// K2: per-(b,g) chain scan. 256 blocks x 1024 threads; 4 timesteps/thread.
// Closed-form Welford via masked prefix sums (S=sum k*m, Q=sum k*m^2, P=sum k):
//   mean_t = (c0*mu0 + S_t)/cs,  var_t = (v0*max(c0,1)+c0*mu0^2 + Q_t)/cs - mean_t^2
// Fully coalesced float4 IO in [b,g,t] layout; wave-shuffle scan (2 barriers).
// NOTE: mask (bool) and prev_count (int64) are pushed by the harness as int32.
// ---------------------------------------------------------------------------
__global__ __launch_bounds__(1024) void k_scan(const float* __restrict__ mT,
                                               const int* __restrict__ mask,
                                               const int* __restrict__ prev_count,
                                               const float* __restrict__ prev_mean,
                                               const float* __restrict__ prev_var,
                                               float* __restrict__ muT,
                                               float* __restrict__ rstdT,
                                               float* __restrict__ out_count,
                                               float* __restrict__ out_mean,
                                               float* __restrict__ out_var) {
    const int bg = blockIdx.x;            // b*G + g
    const int b = bg >> 5;
    const int tid = threadIdx.x;
    const int t0 = tid * 4;

    const float4 mv = *reinterpret_cast<const float4*>(mT + (size_t)bg * Ln + t0);
    const int4 mki = *reinterpret_cast<const int4*>(mask + b * Ln + t0);
    const float k0 = mki.x ? 1.f : 0.f;
    const float k1 = mki.y ? 1.f : 0.f;
    const float k2 = mki.z ? 1.f : 0.f;
    const float k3 = mki.w ? 1.f : 0.f;

    const float S = k0 * mv.x + k1 * mv.y + k2 * mv.z + k3 * mv.w;
    const float Q = k0 * mv.x * mv.x + k1 * mv.y * mv.y + k2 * mv.z * mv.z + k3 * mv.w * mv.w;
    const float P = k0 + k1 + k2 + k3;

    // inclusive scan across the 64-lane wave (no barriers)
    const int lane = tid & 63;
    const int wv = tid >> 6;              // 16 waves
    float iS = S, iQ = Q, iP = P;
#pragma unroll
    for (int off = 1; off < 64; off <<= 1) {
        const float aS = __shfl_up(iS, off);
        const float aQ = __shfl_up(iQ, off);
        const float aP = __shfl_up(iP, off);
        if (lane >= off) { iS += aS; iQ += aQ; iP += aP; }
    }

    __shared__ float wS[16], wQ[16], wP[16];
    if (lane == 63) { wS[wv] = iS; wQ[wv] = iQ; wP[wv] = iP; }
    __syncthreads();
    if (wv == 0) {
        // lanes 0..15 exclusive-scan the 16 wave totals (width-16 segments)
        float oS = (lane < 16) ? wS[lane] : 0.f;
        float oQ = (lane < 16) ? wQ[lane] : 0.f;
        float oP = (lane < 16) ? wP[lane] : 0.f;
        float tS = oS, tQ = oQ, tP = oP;
#pragma unroll
        for (int off = 1; off < 16; off <<= 1) {
            const float aS = __shfl_up(tS, off, 16);
            const float aQ = __shfl_up(tQ, off, 16);
            const float aP = __shfl_up(tP, off, 16);
            if ((lane & 15) >= off) { tS += aS; tQ += aQ; tP += aP; }
        }
        if (lane < 16) { wS[lane] = tS - oS; wQ[lane] = tQ - oQ; wP[lane] = tP - oP; }
    }
    __syncthreads();

    // block-level exclusive prefix for this thread
    const float eS = wS[wv] + (iS - S);
    const float eQ = wQ[wv] + (iQ - Q);
    const float eP = wP[wv] + (iP - P);

    const float c0  = (float)prev_count[b];
    const float mu0 = prev_mean[bg];
    const float v0  = prev_var[bg];
    const float A0  = c0 * mu0;
    const float M2b = v0 * fmaxf(c0, 1.f) + c0 * mu0 * mu0;

    float rS = eS, rQ = eQ, rP = eP;
    float4 om, os;
    {
        rS += k0 * mv.x; rQ += k0 * mv.x * mv.x; rP += k0;
        const float rc = __builtin_amdgcn_rcpf(fmaxf(c0 + rP, 1.f));
        om.x = (A0 + rS) * rc;
        const float var = (M2b + rQ) * rc - om.x * om.x;
        os.x = rsqrtf(var + EPS);
    }
    {
        rS += k1 * mv.y; rQ += k1 * mv.y * mv.y; rP += k1;
        const float rc = __builtin_amdgcn_rcpf(fmaxf(c0 + rP, 1.f));
        om.y = (A0 + rS) * rc;
        const float var = (M2b + rQ) * rc - om.y * om.y;
        os.y = rsqrtf(var + EPS);
    }
    {
        rS += k2 * mv.z; rQ += k2 * mv.z * mv.z; rP += k2;
        const float rc = __builtin_amdgcn_rcpf(fmaxf(c0 + rP, 1.f));
        om.z = (A0 + rS) * rc;
        const float var = (M2b + rQ) * rc - om.z * om.z;
        os.z = rsqrtf(var + EPS);
    }
    {
        rS += k3 * mv.w; rQ += k3 * mv.w * mv.w; rP += k3;
        const float rc = __builtin_amdgcn_rcpf(fmaxf(c0 + rP, 1.f));
        om.w = (A0 + rS) * rc;
        const float var = (M2b + rQ) * rc - om.w * om.w;
        os.w = rsqrtf(var + EPS);
    }

    *reinterpret_cast<float4*>(muT   + (size_t)bg * Ln + t0) = om;
    *reinterpret_cast<float4*>(rstdT + (size_t)bg * Ln + t0) = os;

    if (tid == 1023) {                    // owns t = Ln-1
        const float c = c0 + rP;
        const float cs = fmaxf(c, 1.f);
        out_mean[bg] = om.w;
        out_var[bg]  = (M2b + rQ) / cs - om.w * om.w;
        if ((bg & 31) == 0) out_count[b] = c;
    }
}

// ---------------------------------------------------------------------------
// K3: normalize + affine. Grid-stride over rows; mu/rstd broadcast loads.
// ---------------------------------------------------------------------------
__global__ __launch_bounds__(256) void k_norm(const float* __restrict__ x,
                                              const float* __restrict__ muT,
                                              const float* __restrict__ rstdT,
                                              const float* __restrict__ w,
                                              const float* __restrict__ bias,
                                              float* __restrict__ y) {
    const int tid = threadIdx.x;
    const int g = tid >> 3;
    const float4* wr = reinterpret_cast<const float4*>(w) + tid * 2;
    const float4* br = reinterpret_cast<const float4*>(bias) + tid * 2;
    const float4 wv0 = wr[0], wv1 = wr[1];
    const float4 bv0 = br[0], bv1 = br[1];
    for (int row = blockIdx.x; row < Bn * Ln; row += gridDim.x) {
        const int b = row >> 12;
        const int t = row & (Ln - 1);
        const size_t gi = ((size_t)(b * Gn + g)) * Ln + t;
        const float mean = muT[gi];
        const float rs   = rstdT[gi];
        const float4* xr = reinterpret_cast<const float4*>(x + (size_t)row * Dn) + tid * 2;
        float4* yr = reinterpret_cast<float4*>(y + (size_t)row * Dn) + tid * 2;
        const float4 xv0 = xr[0];
        const float4 xv1 = xr[1];
        float4 o0, o1;
        o0.x = (xv0.x - mean) * rs * wv0.x + bv0.x;
        o0.y = (xv0.y - mean) * rs * wv0.y + bv0.y;
        o0.z = (xv0.z - mean) * rs * wv0.z + bv0.z;
        o0.w = (xv0.w - mean) * rs * wv0.w + bv0.w;
        o1.x = (xv1.x - mean) * rs * wv1.x + bv1.x;
        o1.y = (xv1.y - mean) * rs * wv1.y + bv1.y;
        o1.z = (xv1.z - mean) * rs * wv1.z + bv1.z;
        o1.w = (xv1.w - mean) * rs * wv1.w + bv1.w;
        yr[0] = o0;
        yr[1] = o1;
    }
}

// ---------------------------------------------------------------------------
extern "C" void kernel_launch(void* const* d_in, const int* in_sizes, int n_in,
                              void* d_out, int out_size, void* d_ws, size_t ws_size,
                              hipStream_t stream) {
    (void)in_sizes; (void)n_in; (void)out_size; (void)ws_size;

    const float* x          = (const float*)d_in[0];
    const int*   mask       = (const int*)d_in[1];     // bool pushed as int32
    const int*   prev_count = (const int*)d_in[2];     // int pushed as int32
    const float* prev_mean  = (const float*)d_in[3];
    const float* prev_var   = (const float*)d_in[4];
    const float* weight     = (const float*)d_in[5];
    const float* bias       = (const float*)d_in[6];

    float* out = (float*)d_out;
    float* y         = out;                                   // B*L*D
    float* out_count = out + (size_t)Bn * Ln * Dn;            // B
    float* out_mean  = out_count + Bn;                        // B*G
    float* out_var   = out_mean + (size_t)Bn * Gn;            // B*G

    // workspace: mT | muT | rstdT, each B*G*L floats (4 MiB each), [b,g,t]
    const size_t nBLG = (size_t)Bn * Ln * Gn;
    float* mT    = (float*)d_ws;
    float* muT   = mT + nBLG;
    float* rstdT = muT + nBLG;

    k_group_means<<<2048, 256, 0, stream>>>(x, mT);
    k_scan<<<Bn * Gn, 1024, 0, stream>>>(mT, mask, prev_count, prev_mean, prev_var,
                                         muT, rstdT, out_count, out_mean, out_var);
    k_norm<<<2048, 256, 0, stream>>>(x, muT, rstdT, weight, bias, y);
}